// Round 18
// baseline (231.526 us; speedup 1.0000x reference)
//
#include <hip/hip_runtime.h>
#include <hip/hip_bf16.h>

#define NN 50000      // nodes
#define NE 800000     // edges
#define NR 20         // relations
#define NB 8          // bases
#define D  128        // hidden dim
#define DO 64         // output dim
#define NT 782        // ceil(NN/64) dst tiles
#define NRB (NT*NR)   // (tile,rel) buckets = 15,640

typedef __attribute__((ext_vector_type(8))) short short8;
typedef __attribute__((ext_vector_type(4))) float f32x4;

__device__ inline unsigned short f2bf(float f) {
    __hip_bfloat16 h = __float2bfloat16(f);
    return *reinterpret_cast<unsigned short*>(&h);
}
__device__ inline float bf2f(unsigned short u) {
    unsigned x = ((unsigned)u) << 16;
    float f;
    __builtin_memcpy(&f, &x, 4);
    return f;
}

// ---------------------------------------------------------------------------
// ws layout (bytes):
//   [0        ..  4,003,840) cnt2   NBKT=1,000,960 int -- zeroed (h1 + local scans)
//   [4,003,840..  4,066,400) cntR   NRB int            -- zeroed
//   [4,066,432..  4,129,000) boffR  NRB+1 int
//   [4,129,024..  4,191,584) gcurR  NRB int
//   [4,191,616..  4,201,856) W0     NR*D f32
//   [4,201,856..  4,857,216) W1b    NR*16384 bf16 (B-fragment order)
//   [4,857,216.. 17,657,216) h1b    NN*D bf16
//   [17,657,216..20,857,216) epack2 NE int ((rel<<22)|(dl<<16)|src, by (tile,rel))
//   [20,857,216..20,873,600) linWb  lin_w in B-fragment order, bf16
// ---------------------------------------------------------------------------

// Fused hist+weights, role-split:
//   blocks 0..781  : per-(tile,rel,dl) cnt2 + per-(tile,rel) cntR histograms
//   blocks 782..821: weights build (idx = (b-782)*1024 + t covers 40960)
__global__ __launch_bounds__(1024) void k_wh(
        const int* __restrict__ dst, const int* __restrict__ et,
        const float* __restrict__ basis0, const float* __restrict__ wcomp0,
        const float* __restrict__ basis1, const float* __restrict__ wcomp1,
        const float* __restrict__ lin_w,
        int* __restrict__ cnt2, int* __restrict__ cntR,
        float* __restrict__ W0, unsigned short* __restrict__ W1b,
        unsigned short* __restrict__ linWb) {
    int b = blockIdx.x;
    if (b < NT) {
        int i = b * 1024 + threadIdx.x;
        if (i < NE) {
            int d = dst[i], e = et[i];
            atomicAdd(&cnt2[(d >> 6) * 1280 + e * 64 + (d & 63)], 1);
            atomicAdd(&cntR[(d >> 6) * NR + e], 1);
        }
        return;
    }
    int idx = (b - NT) * 1024 + threadIdx.x;    // 0..40959
    if (idx < NR * D) {
        int r = idx / D, o = idx % D;
        float a = 0.f;
        #pragma unroll
        for (int bb = 0; bb < NB; bb++) a += wcomp0[r * NB + bb] * basis0[bb * D + o];
        W0[idx] = a;
    }
    if (idx < 16 * 64) {
        int lane = idx & 63, fr = idx >> 6;
        int kc = fr >> 2, nt = fr & 3;
        int i0 = kc * 32 + (lane >> 4) * 8;
        int o = nt * 16 + (lane & 15);
        short8 v;
        #pragma unroll
        for (int e = 0; e < 8; e++) v[e] = (short)f2bf(lin_w[(i0 + e) * DO + o]);
        *((short8*)linWb + idx) = v;
    }
    if (idx < NR * 4 * 8 * 64) {
        int lane = idx & 63;
        int cb   = (idx >> 6) & 7;
        int kc   = (idx >> 9) & 3;
        int rel  = idx >> 11;
        float wc[NB];
        #pragma unroll
        for (int bb = 0; bb < NB; bb++) wc[bb] = wcomp1[rel * NB + bb];
        int o  = cb * 16 + (lane & 15);
        int i0 = kc * 32 + (lane >> 4) * 8;
        short8 v;
        #pragma unroll
        for (int e = 0; e < 8; e++) {
            int i = i0 + e;
            float a = 0.f;
            #pragma unroll
            for (int bb = 0; bb < NB; bb++) a += wc[bb] * basis1[(bb * D + i) * D + o];
            v[e] = (short)f2bf(a);
        }
        *((short8*)W1b + idx) = v;
    }
}

// Single-block exclusive scan over the 15,640 (tile,rel) counts.
__global__ __launch_bounds__(1024) void k_scanR(const int* __restrict__ cntR,
                                                int* __restrict__ boffR,
                                                int* __restrict__ gcurR) {
    __shared__ int ws[16];
    int t = threadIdx.x, lane = t & 63, wv = t >> 6;
    int v[16]; int s = 0;
    #pragma unroll
    for (int j = 0; j < 16; j++) {
        int idx = t * 16 + j;
        v[j] = (idx < NRB) ? cntR[idx] : 0;
        s += v[j];
    }
    int inc = s;
    for (int dd = 1; dd < 64; dd <<= 1) {
        int u = __shfl_up(inc, dd);
        if (lane >= dd) inc += u;
    }
    if (lane == 63) ws[wv] = inc;
    __syncthreads();
    if (t == 0) { int a = 0; for (int i = 0; i < 16; i++) { int x = ws[i]; ws[i] = a; a += x; } }
    __syncthreads();
    int base = ws[wv] + inc - s;
    #pragma unroll
    for (int j = 0; j < 16; j++) {
        int idx = t * 16 + j;
        if (idx < NRB) { boffR[idx] = base; gcurR[idx] = base; }
        base += v[j];
    }
    if (t == 1023) boffR[NRB] = base;
}

// Fused scatter+h1, role-split:
//   blocks 0..781   : scatter epack2[pos] = (rel<<22)|(dl<<16)|src by (tile,rel)
//   blocks 782..1563: h1 compute (tile = b - 782)
__global__ __launch_bounds__(1024) void k_sh(
        const int* __restrict__ src, const int* __restrict__ dst,
        const int* __restrict__ et, int* __restrict__ gcurR,
        int* __restrict__ epack2,
        const int* __restrict__ cnt2, const float* __restrict__ W0,
        const float* __restrict__ bias0, unsigned short* __restrict__ h1b) {
    int b = blockIdx.x, t = threadIdx.x;
    if (b < NT) {
        int i = b * 1024 + t;
        if (i < NE) {
            int d = dst[i], e = et[i];
            int pos = atomicAdd(&gcurR[(d >> 6) * NR + e], 1);
            epack2[pos] = (e << 22) | ((d & 63) << 16) | src[i];
        }
        return;
    }
    __shared__ float cs[NR * 64];
    __shared__ float w0s[NR * D];
    int tile = b - NT;
    for (int j = t; j < NR * 64; j += 1024) cs[j] = (float)cnt2[tile * 1280 + j];
    for (int j = t; j < NR * D; j += 1024) w0s[j] = W0[j];
    __syncthreads();
    int nl = t >> 4, cg = t & 15;
    int n = tile * 64 + nl;
    if (n < NN) {
        float a[8];
        #pragma unroll
        for (int j = 0; j < 8; j++) a[j] = bias0[cg * 8 + j];
        for (int r = 0; r < NR; r++) {
            float c = cs[r * 64 + nl];
            #pragma unroll
            for (int j = 0; j < 8; j++) a[j] += c * w0s[r * D + cg * 8 + j];
        }
        short8 o;
        #pragma unroll
        for (int j = 0; j < 8; j++) o[j] = (short)f2bf(fmaxf(a[j], 0.f));
        *((short8*)(h1b + n * D + cg * 8)) = o;
    }
}

// Mega v13 = r15/r17-proven main loop + LOCAL bucket build (replaces the
// global 1M scan): prologue scans the tile's 1280 cnt2 counts block-wide
// (identical offsets to the old global scan), stages the tile's packed
// edges, and LDS-counting-scatters them into dl-sorted epk. stag/lcur
// alias the dead Raw/Sl regions (no LDS growth). Main loop/epilogue
// byte-identical to r17 (94 us profiled).
__global__ __launch_bounds__(512, 2) void k_mega(
        const int* __restrict__ epack2, const int* __restrict__ boffR,
        const int* __restrict__ cnt2,
        const unsigned short* __restrict__ h1b,
        const unsigned short* __restrict__ W1b,
        const unsigned short* __restrict__ linWb,
        const float* __restrict__ bias1, const float* __restrict__ lin_b,
        float* __restrict__ out) {
    __shared__ __align__(16) char lds[17408 + 16384];  // Raw 64x17s8 | Sl 64x16s8
    __shared__ unsigned short ooffs[1282];             // tile-relative offsets
    __shared__ unsigned short epk[2048];               // dl-sorted src ids
    __shared__ int swsc[8];

    short8* Raw8 = (short8*)lds;
    short8* Sl8  = (short8*)(lds + 17408);
    int* stag = (int*)lds;                   // 8 KB, aliases Raw (prologue only)
    int* lcur = (int*)(lds + 17408);         // 5 KB, aliases Sl (prologue only)

    int t = threadIdx.x, tile = blockIdx.x;
    int wv = t >> 6, lane = t & 63;
    int le = t >> 3, lp = t & 7;             // stage role: edge row, 16B pair
    int dl = t >> 3, cg = t & 7;             // reduce role: dst-local, col-group
    int row = lane & 15, gg = lane >> 4;     // mfma role

    // ---- prologue 1: local exclusive scan of cnt2[tile's 1280] -> ooffs ----
    int tb = boffR[tile * NR];
    int b3 = t * 3;
    int c0 = (b3     < 1280) ? cnt2[tile * 1280 + b3]     : 0;
    int c1 = (b3 + 1 < 1280) ? cnt2[tile * 1280 + b3 + 1] : 0;
    int c2 = (b3 + 2 < 1280) ? cnt2[tile * 1280 + b3 + 2] : 0;
    int s3 = c0 + c1 + c2;
    int inc = s3;
    for (int dd = 1; dd < 64; dd <<= 1) {
        int u = __shfl_up(inc, dd);
        if (lane >= dd) inc += u;
    }
    if (lane == 63) swsc[wv] = inc;
    __syncthreads();
    if (t == 0) { int a = 0; for (int j = 0; j < 8; j++) { int x = swsc[j]; swsc[j] = a; a += x; } }
    __syncthreads();
    int base = swsc[wv] + inc - s3;
    if (b3     < 1280) ooffs[b3]     = (unsigned short)base;
    if (b3 + 1 < 1280) ooffs[b3 + 1] = (unsigned short)(base + c0);
    if (b3 + 2 < 1280) ooffs[b3 + 2] = (unsigned short)(base + c0 + c1);
    if (t == 511) ooffs[1280] = (unsigned short)(base + s3);
    __syncthreads();

    // ---- prologue 2: stage packed edges + dl-sort into epk ----
    int cntT = min((int)ooffs[1280], 2048);
    for (int i = t; i < 1280; i += 512) lcur[i] = ooffs[i];
    for (int j = t; j < cntT; j += 512) stag[j] = epack2[tb + j];
    __syncthreads();
    for (int j = t; j < cntT; j += 512) {
        int e = stag[j];
        int key = ((e >> 22) & 31) * 64 + ((e >> 16) & 63);
        int pos = atomicAdd(&lcur[key], 1);
        if (pos < 2048) epk[pos] = (unsigned short)(e & 0xFFFF);
    }
    __syncthreads();

    // ---- main loop (r17-proven, unchanged) ----
    f32x4 acc[4];
    #pragma unroll
    for (int j = 0; j < 4; j++) acc[j] = (f32x4){0.f, 0.f, 0.f, 0.f};

    for (int r = 0; r < NR; r++) {
        int rbase = ooffs[r * 64];
        int cnt = ooffs[r * 64 + 64] - rbase;    // block-uniform
        if (cnt == 0) continue;

        const short8* Wg8 = (const short8*)W1b + r * 2048;
        short8 breg[4];
        #pragma unroll
        for (int kc = 0; kc < 4; kc++) breg[kc] = Wg8[(kc * 8 + wv) * 64 + lane];

        float s[16];
        #pragma unroll
        for (int k = 0; k < 16; k++) s[k] = 0.f;
        int o0 = ooffs[r * 64 + dl] - rbase;
        int o1 = ooffs[r * 64 + dl + 1] - rbase;
        int nc = (cnt + 63) >> 6;

        for (int c = 0; c < nc; c++) {
            int cb0 = c * 64, m = min(64, cnt - cb0);
            if (c > 0) __syncthreads();          // prev reduce done, Raw reusable
            if (le < m) {
                int node = epk[rbase + cb0 + le];
                const short8* hp = (const short8*)(h1b + (size_t)node * D) + lp * 2;
                Raw8[le * 17 + lp * 2]     = hp[0];
                Raw8[le * 17 + lp * 2 + 1] = hp[1];
            }
            __syncthreads();                     // Raw visible
            int lo = max(o0 - cb0, 0), hi = min(o1 - cb0, m);
            for (int p = lo; p < hi; p++) {
                short8 w0 = Raw8[p * 17 + 2 * cg];
                short8 w1 = Raw8[p * 17 + 2 * cg + 1];
                #pragma unroll
                for (int k = 0; k < 8; k++) {
                    s[k]     += bf2f((unsigned short)w0[k]);
                    s[8 + k] += bf2f((unsigned short)w1[k]);
                }
            }
        }
        short8 p0, p1;
        #pragma unroll
        for (int k = 0; k < 8; k++) {
            p0[k] = (short)f2bf(s[k]);
            p1[k] = (short)f2bf(s[8 + k]);
        }
        Sl8[dl * 16 + ((cg * 2)     ^ (dl & 15))] = p0;
        Sl8[dl * 16 + ((cg * 2 + 1) ^ (dl & 15))] = p1;
        __syncthreads();                         // Sl visible (all reduces done)
        #pragma unroll
        for (int rb = 0; rb < 4; rb++) {
            int arow = rb * 16 + row;
            #pragma unroll
            for (int kc = 0; kc < 4; kc++) {
                short8 a = Sl8[arow * 16 + ((kc * 4 + gg) ^ (arow & 15))];
                acc[rb] = __builtin_amdgcn_mfma_f32_16x16x32_bf16(a, breg[kc], acc[rb], 0, 0, 0);
            }
        }
    }

    __syncthreads();                             // last-rel Sl reads done
    // epilogue part 1: bias + relu -> bf16 Af[64][136] (aliases Raw region)
    unsigned short* Af = (unsigned short*)lds;
    #pragma unroll
    for (int rb = 0; rb < 4; rb++) {
        #pragma unroll
        for (int reg = 0; reg < 4; reg++) {
            int rr = rb * 16 + gg * 4 + reg;
            int col = wv * 16 + row;
            Af[rr * 136 + col] = f2bf(fmaxf(acc[rb][reg] + bias1[col], 0.f));
        }
    }
    __syncthreads();
    // epilogue part 2: out[64x64] = Af @ lin_w + lin_b via MFMA
    {
        int rb = wv & 3;
        int nt0 = (wv >> 2) * 2, nt1 = nt0 + 1;
        f32x4 ao0 = (f32x4){0.f, 0.f, 0.f, 0.f};
        f32x4 ao1 = (f32x4){0.f, 0.f, 0.f, 0.f};
        #pragma unroll
        for (int kc = 0; kc < 4; kc++) {
            short8 a = *(const short8*)(Af + (rb * 16 + row) * 136 + kc * 32 + gg * 8);
            short8 b0 = *((const short8*)linWb + (kc * 4 + nt0) * 64 + lane);
            short8 b1 = *((const short8*)linWb + (kc * 4 + nt1) * 64 + lane);
            ao0 = __builtin_amdgcn_mfma_f32_16x16x32_bf16(a, b0, ao0, 0, 0, 0);
            ao1 = __builtin_amdgcn_mfma_f32_16x16x32_bf16(a, b1, ao1, 0, 0, 0);
        }
        float lb0 = lin_b[nt0 * 16 + row];
        float lb1 = lin_b[nt1 * 16 + row];
        #pragma unroll
        for (int reg = 0; reg < 4; reg++) {
            int d = tile * 64 + rb * 16 + gg * 4 + reg;
            if (d < NN) {
                out[d * DO + nt0 * 16 + row] = ao0[reg] + lb0;
                out[d * DO + nt1 * 16 + row] = ao1[reg] + lb1;
            }
        }
    }
}

extern "C" void kernel_launch(void* const* d_in, const int* in_sizes, int n_in,
                              void* d_out, int out_size, void* d_ws, size_t ws_size,
                              hipStream_t stream) {
    const int*   src    = (const int*)d_in[0];
    const int*   dst    = (const int*)d_in[1];
    const int*   et     = (const int*)d_in[2];
    const float* basis0 = (const float*)d_in[4];
    const float* wcomp0 = (const float*)d_in[5];
    const float* bias0  = (const float*)d_in[6];
    const float* basis1 = (const float*)d_in[7];
    const float* wcomp1 = (const float*)d_in[8];
    const float* bias1  = (const float*)d_in[9];
    const float* lin_w  = (const float*)d_in[10];
    const float* lin_b  = (const float*)d_in[11];
    float* out = (float*)d_out;

    char* ws = (char*)d_ws;
    int*            cnt2   = (int*)           (ws + 0);
    int*            cntR   = (int*)           (ws + 4003840);
    int*            boffR  = (int*)           (ws + 4066432);
    int*            gcurR  = (int*)           (ws + 4129024);
    float*          W0     = (float*)         (ws + 4191616);
    unsigned short* W1b    = (unsigned short*)(ws + 4201856);
    unsigned short* h1b    = (unsigned short*)(ws + 4857216);
    int*            epack2 = (int*)           (ws + 17657216);
    unsigned short* linWb  = (unsigned short*)(ws + 20857216);

    hipMemsetAsync(ws, 0, 4066400, stream);   // zero cnt2 + cntR

    k_wh<<<NT + 40, 1024, 0, stream>>>(dst, et, basis0, wcomp0, basis1, wcomp1,
                                       lin_w, cnt2, cntR, W0, W1b, linWb);
    k_scanR<<<1, 1024, 0, stream>>>(cntR, boffR, gcurR);
    k_sh<<<NT * 2, 1024, 0, stream>>>(src, dst, et, gcurR, epack2,
                                      cnt2, W0, bias0, h1b);
    k_mega<<<NT, 512, 0, stream>>>(epack2, boffR, cnt2, h1b, W1b, linWb,
                                   bias1, lin_b, out);
}

// Round 19
// 186.698 us; speedup vs baseline: 1.2401x; 1.2401x over previous
//
#include <hip/hip_runtime.h>
#include <hip/hip_bf16.h>

#define NN 50000      // nodes
#define NE 800000     // edges
#define NR 20         // relations
#define NB 8          // bases
#define D  128        // hidden dim
#define DO 64         // output dim
#define NT 782        // ceil(NN/64) dst tiles
#define NBKT (NT*1280) // (tile, rel, dl) buckets = 1,000,960
#define NSB 978       // ceil(NBKT/1024)

typedef __attribute__((ext_vector_type(8))) short short8;
typedef __attribute__((ext_vector_type(4))) float f32x4;

__device__ inline unsigned short f2bf(float f) {
    __hip_bfloat16 h = __float2bfloat16(f);
    return *reinterpret_cast<unsigned short*>(&h);
}
__device__ inline float bf2f(unsigned short u) {
    unsigned x = ((unsigned)u) << 16;
    float f;
    __builtin_memcpy(&f, &x, 4);
    return f;
}

// ---------------------------------------------------------------------------
// ws layout (bytes):
//   [0        ..  4,003,840) cnt2    NBKT int  -- zeroed each call
//   [4,003,840..  4,007,752) bsum    NSB int   -- rewritten by scan1 (raw totals)
//   [4,007,808..  8,011,652) boff2   NBKT+1 int
//   [8,011,712.. 12,015,552) gcur2   NBKT int
//   [12,015,616..12,025,856) W0      NR*D f32
//   [12,025,856..12,681,216) W1b     NR*16384 bf16 (B-fragment order)
//   [12,681,216..25,481,216) h1b     NN*D bf16
//   [25,481,216..27,081,216) epack   NE ushort (src ids, sorted by (tile,r,dl))
//   [28,681,216..28,697,600) linWb   lin_w in B-fragment order, bf16
// ---------------------------------------------------------------------------

// Fused hist+weights, role-split (no mixed-role straggler blocks):
//   blocks 0..781  : (tile,rel,dl) histogram only
//   blocks 782..821: weights build only (idx = (b-782)*1024 + t covers 40960)
__global__ __launch_bounds__(1024) void k_wh(
        const int* __restrict__ dst, const int* __restrict__ et,
        const float* __restrict__ basis0, const float* __restrict__ wcomp0,
        const float* __restrict__ basis1, const float* __restrict__ wcomp1,
        const float* __restrict__ lin_w,
        int* __restrict__ cnt2, float* __restrict__ W0,
        unsigned short* __restrict__ W1b, unsigned short* __restrict__ linWb) {
    int b = blockIdx.x;
    if (b < NT) {
        int i = b * 1024 + threadIdx.x;
        if (i < NE) {
            int d = dst[i];
            int key = (d >> 6) * 1280 + et[i] * 64 + (d & 63);
            atomicAdd(&cnt2[key], 1);
        }
        return;
    }
    int idx = (b - NT) * 1024 + threadIdx.x;    // 0..40959
    if (idx < NR * D) {
        int r = idx / D, o = idx % D;
        float a = 0.f;
        #pragma unroll
        for (int bb = 0; bb < NB; bb++) a += wcomp0[r * NB + bb] * basis0[bb * D + o];
        W0[idx] = a;
    }
    if (idx < 16 * 64) {
        int lane = idx & 63, fr = idx >> 6;
        int kc = fr >> 2, nt = fr & 3;
        int i0 = kc * 32 + (lane >> 4) * 8;
        int o = nt * 16 + (lane & 15);
        short8 v;
        #pragma unroll
        for (int e = 0; e < 8; e++) v[e] = (short)f2bf(lin_w[(i0 + e) * DO + o]);
        *((short8*)linWb + idx) = v;
    }
    if (idx < NR * 4 * 8 * 64) {
        int lane = idx & 63;
        int cb   = (idx >> 6) & 7;
        int kc   = (idx >> 9) & 3;
        int rel  = idx >> 11;
        float wc[NB];
        #pragma unroll
        for (int bb = 0; bb < NB; bb++) wc[bb] = wcomp1[rel * NB + bb];
        int o  = cb * 16 + (lane & 15);
        int i0 = kc * 32 + (lane >> 4) * 8;
        short8 v;
        #pragma unroll
        for (int e = 0; e < 8; e++) {
            int i = i0 + e;
            float a = 0.f;
            #pragma unroll
            for (int bb = 0; bb < NB; bb++) a += wc[bb] * basis1[(bb * D + i) * D + o];
            v[e] = (short)f2bf(a);
        }
        *((short8*)W1b + idx) = v;
    }
}

__global__ __launch_bounds__(1024) void k_scan1(const int* __restrict__ cnt2,
                                                int* __restrict__ boff2,
                                                int* __restrict__ bsum) {
    __shared__ int ws[16];
    int t = threadIdx.x, lane = t & 63, wv = t >> 6;
    int i = blockIdx.x * 1024 + t;
    int v = (i < NBKT) ? cnt2[i] : 0;
    int inc = v;
    for (int dd = 1; dd < 64; dd <<= 1) {
        int u = __shfl_up(inc, dd);
        if (lane >= dd) inc += u;
    }
    if (lane == 63) ws[wv] = inc;
    __syncthreads();
    if (t == 0) { int a = 0; for (int j = 0; j < 16; j++) { int x = ws[j]; ws[j] = a; a += x; } }
    __syncthreads();
    int ex = ws[wv] + inc - v;
    if (i < NBKT) boff2[i] = ex;
    if (t == 1023) bsum[blockIdx.x] = ex + v;   // raw block total (not scanned)
}

// scan3 with scan2 folded in: block b computes sum(bsum[0..b-1]) itself
// (one 1024-thread reduction over the L2-hot 978-entry bsum array).
__global__ __launch_bounds__(1024) void k_scan3(int* __restrict__ boff2,
                                                const int* __restrict__ bsum,
                                                int* __restrict__ gcur2) {
    __shared__ int ws[16];
    __shared__ int basesh;
    int t = threadIdx.x, lane = t & 63, wv = t >> 6;
    int b = blockIdx.x;
    int v = (t < b) ? bsum[t] : 0;               // b <= 977 < 1024: one pass
    #pragma unroll
    for (int dd = 1; dd < 64; dd <<= 1) v += __shfl_xor(v, dd);
    if (lane == 0) ws[wv] = v;
    __syncthreads();
    if (t == 0) { int a = 0; for (int j = 0; j < 16; j++) a += ws[j]; basesh = a; }
    __syncthreads();
    int base = basesh;
    int i = b * 1024 + t;
    if (i < NBKT) {
        int f = boff2[i] + base;
        boff2[i] = f;
        gcur2[i] = f;
    }
    if (i == 0) boff2[NBKT] = NE;
}

// Fused scatter+h1, role-split:
//   blocks 0..781   : counting-sort scatter only
//   blocks 782..1563: h1 compute only (tile = b - 782)
__global__ __launch_bounds__(1024) void k_sh(
        const int* __restrict__ src, const int* __restrict__ dst,
        const int* __restrict__ et, int* __restrict__ gcur2,
        unsigned short* __restrict__ epack,
        const int* __restrict__ cnt2, const float* __restrict__ W0,
        const float* __restrict__ bias0, unsigned short* __restrict__ h1b) {
    int b = blockIdx.x, t = threadIdx.x;
    if (b < NT) {
        int i = b * 1024 + t;
        if (i < NE) {
            int d = dst[i];
            int key = (d >> 6) * 1280 + et[i] * 64 + (d & 63);
            int pos = atomicAdd(&gcur2[key], 1);
            epack[pos] = (unsigned short)src[i];
        }
        return;
    }
    __shared__ float cs[NR * 64];
    __shared__ float w0s[NR * D];
    int tile = b - NT;
    for (int j = t; j < NR * 64; j += 1024) cs[j] = (float)cnt2[tile * 1280 + j];
    for (int j = t; j < NR * D; j += 1024) w0s[j] = W0[j];
    __syncthreads();
    int nl = t >> 4, cg = t & 15;              // node-local, col-group of 8
    int n = tile * 64 + nl;
    if (n < NN) {
        float a[8];
        #pragma unroll
        for (int j = 0; j < 8; j++) a[j] = bias0[cg * 8 + j];
        for (int r = 0; r < NR; r++) {
            float c = cs[r * 64 + nl];
            #pragma unroll
            for (int j = 0; j < 8; j++) a[j] += c * w0s[r * D + cg * 8 + j];
        }
        short8 o;
        #pragma unroll
        for (int j = 0; j < 8; j++) o[j] = (short)f2bf(fmaxf(a[j], 0.f));
        *((short8*)(h1b + n * D + cg * 8)) = o;
    }
}

// Mega v12 (r15/r17-proven, 94.1 us profiled): r13 body + epk/ooffs in LDS.
// 512 thr / 64-dst tile; wave wv owns output cols wv*16..+15 for all 64 rows.
// Per rel: 4 B-frag register loads (reused 4x) at rel-top; stage 64 rows ->
// Raw (node ids from LDS epk); reduce own bucket; publish swizzled Sl;
// 16 MFMA. 2 barriers/rel. No pipelining, no setprio (r16 showed both hurt).
__global__ __launch_bounds__(512, 2) void k_mega(
        const unsigned short* __restrict__ epack, const int* __restrict__ boff2,
        const unsigned short* __restrict__ h1b,
        const unsigned short* __restrict__ W1b,
        const unsigned short* __restrict__ linWb,
        const float* __restrict__ bias1, const float* __restrict__ lin_b,
        float* __restrict__ out) {
    __shared__ __align__(16) char lds[17408 + 16384];  // Raw 64x17s8 | Sl 64x16s8
    __shared__ unsigned short ooffs[1282];             // tile-relative offsets
    __shared__ unsigned short epk[2048];               // tile's src ids

    short8* Raw8 = (short8*)lds;
    short8* Sl8  = (short8*)(lds + 17408);

    int t = threadIdx.x, tile = blockIdx.x;
    int wv = t >> 6, lane = t & 63;
    int le = t >> 3, lp = t & 7;             // stage role: edge row, 16B pair
    int dl = t >> 3, cg = t & 7;             // reduce role: dst-local, col-group
    int row = lane & 15, gg = lane >> 4;     // mfma role

    int kbase = tile * 1280;
    int tb = boff2[kbase];
    for (int i = t; i < 1281; i += 512)
        ooffs[i] = (unsigned short)(boff2[kbase + i] - tb);
    __syncthreads();
    int nE = min((int)ooffs[1280], 2048);
    for (int i = t; i < nE; i += 512) epk[i] = epack[tb + i];
    __syncthreads();

    f32x4 acc[4];
    #pragma unroll
    for (int j = 0; j < 4; j++) acc[j] = (f32x4){0.f, 0.f, 0.f, 0.f};

    for (int r = 0; r < NR; r++) {
        int rbase = ooffs[r * 64];
        int cnt = ooffs[r * 64 + 64] - rbase;    // block-uniform
        if (cnt == 0) continue;

        const short8* Wg8 = (const short8*)W1b + r * 2048;
        short8 breg[4];
        #pragma unroll
        for (int kc = 0; kc < 4; kc++) breg[kc] = Wg8[(kc * 8 + wv) * 64 + lane];

        float s[16];
        #pragma unroll
        for (int k = 0; k < 16; k++) s[k] = 0.f;
        int o0 = ooffs[r * 64 + dl] - rbase;
        int o1 = ooffs[r * 64 + dl + 1] - rbase;
        int nc = (cnt + 63) >> 6;

        for (int c = 0; c < nc; c++) {
            int cb0 = c * 64, m = min(64, cnt - cb0);
            if (c > 0) __syncthreads();          // prev reduce done, Raw reusable
            if (le < m) {
                int node = epk[rbase + cb0 + le];
                const short8* hp = (const short8*)(h1b + (size_t)node * D) + lp * 2;
                Raw8[le * 17 + lp * 2]     = hp[0];
                Raw8[le * 17 + lp * 2 + 1] = hp[1];
            }
            __syncthreads();                     // Raw visible
            int lo = max(o0 - cb0, 0), hi = min(o1 - cb0, m);
            for (int p = lo; p < hi; p++) {
                short8 w0 = Raw8[p * 17 + 2 * cg];
                short8 w1 = Raw8[p * 17 + 2 * cg + 1];
                #pragma unroll
                for (int k = 0; k < 8; k++) {
                    s[k]     += bf2f((unsigned short)w0[k]);
                    s[8 + k] += bf2f((unsigned short)w1[k]);
                }
            }
        }
        short8 p0, p1;
        #pragma unroll
        for (int k = 0; k < 8; k++) {
            p0[k] = (short)f2bf(s[k]);
            p1[k] = (short)f2bf(s[8 + k]);
        }
        Sl8[dl * 16 + ((cg * 2)     ^ (dl & 15))] = p0;
        Sl8[dl * 16 + ((cg * 2 + 1) ^ (dl & 15))] = p1;
        __syncthreads();                         // Sl visible (all reduces done)
        #pragma unroll
        for (int rb = 0; rb < 4; rb++) {
            int arow = rb * 16 + row;
            #pragma unroll
            for (int kc = 0; kc < 4; kc++) {
                short8 a = Sl8[arow * 16 + ((kc * 4 + gg) ^ (arow & 15))];
                acc[rb] = __builtin_amdgcn_mfma_f32_16x16x32_bf16(a, breg[kc], acc[rb], 0, 0, 0);
            }
        }
    }

    __syncthreads();                             // last-rel Sl reads done
    // epilogue part 1: bias + relu -> bf16 Af[64][136] (aliases Raw region)
    unsigned short* Af = (unsigned short*)lds;
    #pragma unroll
    for (int rb = 0; rb < 4; rb++) {
        #pragma unroll
        for (int reg = 0; reg < 4; reg++) {
            int rr = rb * 16 + gg * 4 + reg;
            int col = wv * 16 + row;
            Af[rr * 136 + col] = f2bf(fmaxf(acc[rb][reg] + bias1[col], 0.f));
        }
    }
    __syncthreads();
    // epilogue part 2: out[64x64] = Af @ lin_w + lin_b via MFMA
    {
        int rb = wv & 3;
        int nt0 = (wv >> 2) * 2, nt1 = nt0 + 1;
        f32x4 ao0 = (f32x4){0.f, 0.f, 0.f, 0.f};
        f32x4 ao1 = (f32x4){0.f, 0.f, 0.f, 0.f};
        #pragma unroll
        for (int kc = 0; kc < 4; kc++) {
            short8 a = *(const short8*)(Af + (rb * 16 + row) * 136 + kc * 32 + gg * 8);
            short8 b0 = *((const short8*)linWb + (kc * 4 + nt0) * 64 + lane);
            short8 b1 = *((const short8*)linWb + (kc * 4 + nt1) * 64 + lane);
            ao0 = __builtin_amdgcn_mfma_f32_16x16x32_bf16(a, b0, ao0, 0, 0, 0);
            ao1 = __builtin_amdgcn_mfma_f32_16x16x32_bf16(a, b1, ao1, 0, 0, 0);
        }
        float lb0 = lin_b[nt0 * 16 + row];
        float lb1 = lin_b[nt1 * 16 + row];
        #pragma unroll
        for (int reg = 0; reg < 4; reg++) {
            int d = tile * 64 + rb * 16 + gg * 4 + reg;
            if (d < NN) {
                out[d * DO + nt0 * 16 + row] = ao0[reg] + lb0;
                out[d * DO + nt1 * 16 + row] = ao1[reg] + lb1;
            }
        }
    }
}

extern "C" void kernel_launch(void* const* d_in, const int* in_sizes, int n_in,
                              void* d_out, int out_size, void* d_ws, size_t ws_size,
                              hipStream_t stream) {
    const int*   src    = (const int*)d_in[0];
    const int*   dst    = (const int*)d_in[1];
    const int*   et     = (const int*)d_in[2];
    const float* basis0 = (const float*)d_in[4];
    const float* wcomp0 = (const float*)d_in[5];
    const float* bias0  = (const float*)d_in[6];
    const float* basis1 = (const float*)d_in[7];
    const float* wcomp1 = (const float*)d_in[8];
    const float* bias1  = (const float*)d_in[9];
    const float* lin_w  = (const float*)d_in[10];
    const float* lin_b  = (const float*)d_in[11];
    float* out = (float*)d_out;

    char* ws = (char*)d_ws;
    int*            cnt2    = (int*)           (ws + 0);
    int*            bsum    = (int*)           (ws + 4003840);
    int*            boff2   = (int*)           (ws + 4007808);
    int*            gcur2   = (int*)           (ws + 8011712);
    float*          W0      = (float*)         (ws + 12015616);
    unsigned short* W1b     = (unsigned short*)(ws + 12025856);
    unsigned short* h1b     = (unsigned short*)(ws + 12681216);
    unsigned short* epack   = (unsigned short*)(ws + 25481216);
    unsigned short* linWb   = (unsigned short*)(ws + 28681216);

    hipMemsetAsync(ws, 0, 4003840, stream);   // zero cnt2

    k_wh<<<NT + 40, 1024, 0, stream>>>(dst, et, basis0, wcomp0, basis1, wcomp1,
                                       lin_w, cnt2, W0, W1b, linWb);
    k_scan1<<<NSB, 1024, 0, stream>>>(cnt2, boff2, bsum);
    k_scan3<<<NSB, 1024, 0, stream>>>(boff2, bsum, gcur2);
    k_sh<<<NT * 2, 1024, 0, stream>>>(src, dst, et, gcur2, epack,
                                      cnt2, W0, bias0, h1b);
    k_mega<<<NT, 512, 0, stream>>>(epack, boff2, h1b, W1b, linWb,
                                   bias1, lin_b, out);
}